// Round 1
// 305.214 us; speedup vs baseline: 1.0267x; 1.0267x over previous
//
#include <hip/hip_runtime.h>

// GlobalQuantizedLatent: per-element nearest-codebook quantization.
// N = 16,777,216 f32, V = 16 codebook entries (linspace(-0.5, 0.5, 16)).
// Outputs (concatenated flat, all f32):
//   [0,   N) : x            (copy of input)
//   [N,  2N) : quantized    (values[argmin |x - values|])
//   [2N, 3N) : z_hat        (== quantized numerically in forward)
//   [3N, 4N) : indices      (argmin index, stored as float)
//
// Memory-bound: 64 MiB read + 256 MiB write => ~53 us floor at 6.3 TB/s.
// This version: nontemporal loads/stores (output is write-once never-re-read;
// input is read-once) to bypass L2/LLC allocation — the harness's 1 GiB
// poison fill leaves both caches full of dirty lines right before we run.
// Grid-stride at 8192 blocks, two float4 chunks per thread, every vector
// memory op perfectly lane-contiguous (16 B/lane).

#define BLOCK 256
#define NVALS 16

typedef float f32x4 __attribute__((ext_vector_type(4)));

__global__ __launch_bounds__(BLOCK) void
GlobalQuantizedLatent_87900800680047_kernel(const float* __restrict__ x,
                                            const float* __restrict__ values,
                                            float* __restrict__ out,
                                            int n) {
    const int tid     = blockIdx.x * BLOCK + threadIdx.x;
    const int nchunks = n >> 2;                 // float4 chunks: 4,194,304
    const int stride  = gridDim.x * BLOCK;      // threads in grid

    // Codebook: wave-uniform pointer + constant offsets -> scalar loads.
    float v[NVALS];
#pragma unroll
    for (int j = 0; j < NVALS; ++j) v[j] = values[j];

    const size_t nn = (size_t)n;
    float* __restrict__ o_q   = out + nn;
    float* __restrict__ o_zh  = out + 2 * nn;
    float* __restrict__ o_idx = out + 3 * nn;

    for (int c = tid; c < nchunks; c += stride) {
        const int i4 = c << 2;

        const f32x4 xv =
            __builtin_nontemporal_load(reinterpret_cast<const f32x4*>(x + i4));

        f32x4 qv, iv;
#pragma unroll
        for (int e = 0; e < 4; ++e) {
            const float xs = xv[e];
            // Exact replication of jnp.argmin(|x - values|): first minimum
            // wins (strict <), matching the reference tie-break bit-for-bit.
            float best = fabsf(xs - v[0]);
            int bi = 0;
#pragma unroll
            for (int j = 1; j < NVALS; ++j) {
                const float d = fabsf(xs - v[j]);
                if (d < best) { best = d; bi = j; }
            }
            qv[e] = v[bi];       // unrolled loop -> cndmask chain, no scratch
            iv[e] = (float)bi;
        }

        __builtin_nontemporal_store(xv, reinterpret_cast<f32x4*>(out + i4));
        __builtin_nontemporal_store(qv, reinterpret_cast<f32x4*>(o_q + i4));
        __builtin_nontemporal_store(qv, reinterpret_cast<f32x4*>(o_zh + i4));
        __builtin_nontemporal_store(iv, reinterpret_cast<f32x4*>(o_idx + i4));
    }
}

extern "C" void kernel_launch(void* const* d_in, const int* in_sizes, int n_in,
                              void* d_out, int out_size, void* d_ws, size_t ws_size,
                              hipStream_t stream) {
    const float* x      = (const float*)d_in[0];
    const float* values = (const float*)d_in[1];
    float* out          = (float*)d_out;
    const int n = in_sizes[0];  // 16,777,216

    // 8192 blocks = 32 blocks/CU; each thread handles 2 float4 chunks via
    // the grid-stride loop (exactly 2 iterations at N = 16,777,216).
    const int grid = 8192;

    GlobalQuantizedLatent_87900800680047_kernel<<<grid, BLOCK, 0, stream>>>(
        x, values, out, n);
}